// Round 12
// baseline (42.270 us; speedup 1.0000x reference)
//
#include <hip/hip_runtime.h>

// TGCN graph convolution, float32 in/out — ONE kernel, ZERO cross-block sync.
// B=4, N=1024, input_dim=1, gru=64 -> D=65, H=8 heads, F=8, out=(B,N,128).
//
// Round 12: R11 (same algorithm) died with an HSA memory-fault abort. Two
// fault candidates fixed: (a) uninitialized LDS read of neighbor entries
// >= cpad — now the full 64-entry row is pre-initialized with (i, 0.0)
// self-loop pads before the CSR build overwrites [0,c); (b) register
// pressure: chunk depth 8 -> 4, no forced-occupancy launch_bounds.
//
// Algorithm (zero cross-block dependency; dur ~= 11.6us/node floor => 1 node):
//   gat_out[i,h,:] = (SUM_j p_ijh * h_j) @ W[:,hF:(h+1)F] / den_h
//   e_src[i,h] = h_i . (W@a_src)[:,h],  e_dst[j,h] = h_j . (W@a_dst)[:,h]
//   lap_out    = (SUM_j lap_ij * h_j) @ weights + bias   (exact ref order)
// A wave owning row i reads only KERNEL INPUTS for its ~31 neighbors.
// Lane layout: h = lane>>3 (head), dg = lane&7; lane owns d-slots d=dg+8t,
// t=0..8 (covers D=65). ~280 MFLOP total ~ 1.8us at 157TF vector.

#define NN 1024
typedef unsigned long long u64;

__global__ __launch_bounds__(256) void fused_one(
    const float* __restrict__ adj,
    const float* __restrict__ lap,
    const float* __restrict__ inp,
    const float* __restrict__ hid,
    const float* __restrict__ W,
    const float* __restrict__ W2,
    const float* __restrict__ attnv,
    const float* __restrict__ biases,
    float* __restrict__ out)
{
    __shared__ float wsrc_s[520], wdst_s[520];   // (W@a_src), (W@a_dst): [d][h]
    __shared__ int   idx_s[4][64];
    __shared__ float lapv_s[4][64];

    const int tid  = threadIdx.x;
    const int wid  = tid >> 6;
    const int lane = tid & 63;
    const int row  = blockIdx.x * 4 + wid;     // (b,i) flat in [0,4096)
    const int b    = row >> 10;
    const int i    = row & (NN - 1);
    const int brow = b << 10;
    const int h    = lane >> 3;                // head
    const int dg   = lane & 7;                 // d-group

    // ---- folded attention projections: wsrc[d*8+h] = sum_f W[d][h*8+f]*a_src[f]
    for (int e = tid; e < 520; e += 256) {
        const int d = e >> 3, hh = e & 7;
        float s1 = 0.f, s2 = 0.f;
        #pragma unroll
        for (int f = 0; f < 8; ++f) {
            const float w = W[d * 64 + hh * 8 + f];
            s1 = fmaf(w, attnv[f],     s1);
            s2 = fmaf(w, attnv[8 + f], s2);
        }
        wsrc_s[e] = s1; wdst_s[e] = s2;
    }

    // ---- pre-init full neighbor row with self-loop pads (NO uninit reads) --
    idx_s[wid][lane]  = i;
    lapv_s[wid][lane] = 0.f;

    // ---- CSR build of own row i (per wave, block-local LDS) ----
    int c;
    {
        const float4* arow = (const float4*)(adj + i * NN);
        const float4* lrow = (const float4*)(lap + i * NN);
        float4 a[4], l[4];
        #pragma unroll
        for (int it = 0; it < 4; ++it) a[it] = arow[it * 64 + lane];
        #pragma unroll
        for (int it = 0; it < 4; ++it) l[it] = lrow[it * 64 + lane];
        const u64 lt = (1ull << lane) - 1ull;
        int base = 0;
        #pragma unroll
        for (int it = 0; it < 4; ++it) {
            const bool m0 = a[it].x != 0.f, m1 = a[it].y != 0.f,
                       m2 = a[it].z != 0.f, m3 = a[it].w != 0.f;
            const u64 b0 = __ballot(m0), b1 = __ballot(m1),
                      b2 = __ballot(m2), b3 = __ballot(m3);
            int pos = base + __popcll(b0 & lt) + __popcll(b1 & lt)
                           + __popcll(b2 & lt) + __popcll(b3 & lt);
            const int j0 = it * 256 + lane * 4;
            if (m0 && pos < 64) { idx_s[wid][pos] = j0;   lapv_s[wid][pos] = l[it].x; ++pos; }
            if (m1 && pos < 64) { idx_s[wid][pos] = j0+1; lapv_s[wid][pos] = l[it].y; ++pos; }
            if (m2 && pos < 64) { idx_s[wid][pos] = j0+2; lapv_s[wid][pos] = l[it].z; ++pos; }
            if (m3 && pos < 64) { idx_s[wid][pos] = j0+3; lapv_s[wid][pos] = l[it].w; }
            base += __popcll(b0) + __popcll(b1) + __popcll(b2) + __popcll(b3);
        }
        c = (base < 64) ? base : 64;           // deg mean ~31, max ~56
    }

    __syncthreads();    // wsrc_s/wdst_s ready (idx/lapv are own-wave-only)

    // ---- per-lane folded weights for its 9 d-slots ----
    float wsr[9], wdr[9];
    #pragma unroll
    for (int t = 0; t < 9; ++t) {
        const int d = dg + 8 * t;
        const bool ok = (d <= 64);
        const int o = (ok ? d : 0) * 8 + h;
        wsr[t] = ok ? wsrc_s[o] : 0.f;
        wdr[t] = ok ? wdst_s[o] : 0.f;
    }

    // neighbor list into registers (fully initialized now)
    const int   j_lane  = idx_s[wid][lane];
    const float lv_lane = lapv_s[wid][lane];

    // ---- e_src of own row: es[h] = h_i . wsrc[:,h] ----
    float es_h;
    {
        const float hvi = hid[row * 64 + lane];
        const float ini = inp[row];
        float e = 0.f;
        #pragma unroll
        for (int t = 0; t < 9; ++t) {
            const int d = dg + 8 * t;
            const int sidx = (d > 0) ? ((d - 1) & 63) : 0;
            float v = __shfl(hvi, sidx);
            if (d == 0) v = ini;
            if (d > 64) v = 0.f;
            e = fmaf(v, wsr[t], e);
        }
        e += __shfl_xor(e, 1); e += __shfl_xor(e, 2); e += __shfl_xor(e, 4);
        es_h = e;
    }

    // ---- main edge loop: 4-deep prefetched chunks ----
    float agg[9], lapa[9];
    #pragma unroll
    for (int t = 0; t < 9; ++t) { agg[t] = 0.f; lapa[t] = 0.f; }
    float den = 0.f;

    for (int kb = 0; kb < c; kb += 4) {
        float hvq[4], inq[4], lvq[4];
        #pragma unroll
        for (int q = 0; q < 4; ++q) {          // issue all 4 loads first (MLP)
            const int k  = kb + q;             // <= 63 always; pads are self
            const int jr = brow | __shfl(j_lane, k);
            hvq[q] = hid[jr * 64 + lane];      // coalesced 256B
            inq[q] = inp[jr];                  // broadcast
            lvq[q] = __shfl(lv_lane, k);
        }
        #pragma unroll
        for (int q = 0; q < 4; ++q) {
            float hd[9];
            float ed = 0.f;
            #pragma unroll
            for (int t = 0; t < 9; ++t) {      // gather h_j[d] via shuffles
                const int d = dg + 8 * t;
                const int sidx = (d > 0) ? ((d - 1) & 63) : 0;
                float v = __shfl(hvq[q], sidx);
                if (d == 0) v = inq[q];
                if (d > 64) v = 0.f;
                hd[t] = v;
                ed = fmaf(v, wdr[t], ed);      // e_dst partial
            }
            ed += __shfl_xor(ed, 1); ed += __shfl_xor(ed, 2); ed += __shfl_xor(ed, 4);
            float s = es_h + ed;
            s = (s > 0.f) ? s : 0.2f * s;      // leaky_relu(0.2)
            const float p = (kb + q < c) ? __expf(s) : 0.f;
            den += p;                          // uniform within 8-lane group
            #pragma unroll
            for (int t = 0; t < 9; ++t) {
                agg[t]  = fmaf(p,      hd[t], agg[t]);   // softmax numerator
                lapa[t] = fmaf(lvq[q], hd[t], lapa[t]);  // laplacian agg
            }
        }
    }

    // ---- finalize: project agg (per head) and lapa through W / weights ----
    float accg = 0.f, accl = 0.f;
    const int gbase = lane & 56;               // own 8-lane head group
    #pragma unroll
    for (int t = 0; t < 9; ++t) {
        #pragma unroll
        for (int dgi = 0; dgi < 8; ++dgi) {
            const int d = 8 * t + dgi;
            if (d <= 64) {
                const float av = __shfl(agg[t],  gbase | dgi);  // agg_h[d]
                const float lv = __shfl(lapa[t], gbase | dgi);  // lapa[d]
                accg = fmaf(av, W [d * 64 + lane], accg);
                accl = fmaf(lv, W2[d * 64 + lane], accl);
            }
        }
    }

    out[row * 128 + lane]      = accg / den;
    out[row * 128 + 64 + lane] = accl + biases[lane];
}

// ---------------------------------------------------------------------------
extern "C" void kernel_launch(void* const* d_in, const int* in_sizes, int n_in,
                              void* d_out, int out_size, void* d_ws, size_t ws_size,
                              hipStream_t stream) {
    const float* inp    = (const float*)d_in[0];  // (4,1024,1)
    const float* hid    = (const float*)d_in[1];  // (4,1024,64)
    const float* W      = (const float*)d_in[2];  // (65,64)
    const float* attnv  = (const float*)d_in[3];  // (16,1)
    const float* W2     = (const float*)d_in[4];  // (65,64) "weights"
    const float* biases = (const float*)d_in[5];  // (64,)
    const float* adj    = (const float*)d_in[6];  // (1024,1024)
    const float* lap    = (const float*)d_in[7];  // (1024,1024)
    float* out = (float*)d_out;
    // d_ws: UNUSED — no workspace, no memset node, no cross-block state.

    fused_one<<<NN, 256, 0, stream>>>(
        adj, lap, inp, hid, W, W2, attnv, biases, out);
}

// Round 13
// 30.812 us; speedup vs baseline: 1.3719x; 1.3719x over previous
//
#include <hip/hip_runtime.h>

// TGCN graph convolution, float32 in/out — ONE kernel, ZERO cross-block sync.
// B=4, N=1024, input_dim=1, gru=64 -> D=65, H=8 heads, F=8, out=(B,N,128).
//
// Model (R2..R12): dur ~= SUM max(~11.6us, kernel_i) per graph node. One
// node absorbs the floor -> goal: single fused kernel < ~20us.
// R12 (same algorithm) ran 43.7us: per-edge h_j gather used 9 ds_bpermute +
// 3 ds_swizzle in DEPENDENT chains (~120cyc LDS latency each, VALUBusy 26%).
// Round 13: identical arithmetic, but
//  - h_j gather = DIRECT global loads hid[jr*64+d-1] (8 dwords x 8-way
//    broadcast per wave-instr, L1-resident rows, independent -> pipelines);
//  - 4-edge batches with statically-indexed hd4[4][9] (rule #20 safe);
//  - final projection via wave-local LDS broadcast (no bpermute);
//  - es via the same direct-load pattern.
// Algorithm: gat[i,h,:] = (SUM_j p_ijh h_j) @ W[:,h-blk] / den_h;
//   e_* folded: wsrc/wdst = W @ a_src/dst (65x8, in LDS per block);
//   lap_out = (SUM_j lap_ij h_j) @ weights + bias (exact ref order).

#define NN 1024
typedef unsigned long long u64;

__global__ __launch_bounds__(256) void fused_one(
    const float* __restrict__ adj,
    const float* __restrict__ lap,
    const float* __restrict__ inp,
    const float* __restrict__ hid,
    const float* __restrict__ W,
    const float* __restrict__ W2,
    const float* __restrict__ attnv,
    const float* __restrict__ biases,
    float* __restrict__ out)
{
    __shared__ float wsrc_s[520], wdst_s[520];   // (W@a_src),(W@a_dst): [d][h]
    __shared__ int   idx_s[4][64];
    __shared__ float lapv_s[4][64];
    __shared__ float agg_s[4][8][72];            // [wid][h][d] (pad 72)
    __shared__ float lapa_s[4][72];              // [wid][d]

    const int tid  = threadIdx.x;
    const int wid  = tid >> 6;
    const int lane = tid & 63;
    const int row  = blockIdx.x * 4 + wid;       // (b,i) flat in [0,4096)
    const int b    = row >> 10;
    const int i    = row & (NN - 1);
    const int brow = b << 10;
    const int h    = lane >> 3;                  // head
    const int dg   = lane & 7;                   // d-group

    // ---- folded attention projections ----
    for (int e = tid; e < 520; e += 256) {
        const int d = e >> 3, hh = e & 7;
        float s1 = 0.f, s2 = 0.f;
        #pragma unroll
        for (int f = 0; f < 8; ++f) {
            const float w = W[d * 64 + hh * 8 + f];
            s1 = fmaf(w, attnv[f],     s1);
            s2 = fmaf(w, attnv[8 + f], s2);
        }
        wsrc_s[e] = s1; wdst_s[e] = s2;
    }

    // ---- pre-init neighbor row with self-loop pads, then CSR build ----
    idx_s[wid][lane]  = i;
    lapv_s[wid][lane] = 0.f;
    int c;
    {
        const float4* arow = (const float4*)(adj + i * NN);
        const float4* lrow = (const float4*)(lap + i * NN);
        float4 a[4], l[4];
        #pragma unroll
        for (int it = 0; it < 4; ++it) a[it] = arow[it * 64 + lane];
        #pragma unroll
        for (int it = 0; it < 4; ++it) l[it] = lrow[it * 64 + lane];
        const u64 lt = (1ull << lane) - 1ull;
        int base = 0;
        #pragma unroll
        for (int it = 0; it < 4; ++it) {
            const bool m0 = a[it].x != 0.f, m1 = a[it].y != 0.f,
                       m2 = a[it].z != 0.f, m3 = a[it].w != 0.f;
            const u64 b0 = __ballot(m0), b1 = __ballot(m1),
                      b2 = __ballot(m2), b3 = __ballot(m3);
            int pos = base + __popcll(b0 & lt) + __popcll(b1 & lt)
                           + __popcll(b2 & lt) + __popcll(b3 & lt);
            const int j0 = it * 256 + lane * 4;
            if (m0 && pos < 64) { idx_s[wid][pos] = j0;   lapv_s[wid][pos] = l[it].x; ++pos; }
            if (m1 && pos < 64) { idx_s[wid][pos] = j0+1; lapv_s[wid][pos] = l[it].y; ++pos; }
            if (m2 && pos < 64) { idx_s[wid][pos] = j0+2; lapv_s[wid][pos] = l[it].z; ++pos; }
            if (m3 && pos < 64) { idx_s[wid][pos] = j0+3; lapv_s[wid][pos] = l[it].w; }
            base += __popcll(b0) + __popcll(b1) + __popcll(b2) + __popcll(b3);
        }
        c = (base < 64) ? base : 64;             // deg mean ~31, max ~56
    }

    __syncthreads();                             // wsrc_s/wdst_s ready

    // ---- per-lane folded weights for the 9 d-slots ----
    float wsr[9], wdr[9];
    #pragma unroll
    for (int t = 0; t < 9; ++t) {
        const int d = dg + 8 * t;
        const bool ok = (d <= 64);
        const int o = (ok ? d : 0) * 8 + h;
        wsr[t] = ok ? wsrc_s[o] : 0.f;
        wdr[t] = ok ? wdst_s[o] : 0.f;
    }

    const int   j_lane  = idx_s[wid][lane];
    const float lv_lane = lapv_s[wid][lane];

    // ---- e_src of own row via direct loads ----
    float es_h;
    {
        float e = 0.f;
        #pragma unroll
        for (int t = 0; t < 9; ++t) {
            const int d = dg + 8 * t;
            float v = 0.f;
            if (d == 0)       v = inp[row];
            else if (d <= 64) v = hid[row * 64 + d - 1];
            e = fmaf(v, wsr[t], e);
        }
        e += __shfl_xor(e, 1); e += __shfl_xor(e, 2); e += __shfl_xor(e, 4);
        es_h = e;
    }

    // ---- edge loop: 4-edge batches, direct-load gather (no bpermute) ----
    float agg[9], lapa[9];
    #pragma unroll
    for (int t = 0; t < 9; ++t) { agg[t] = 0.f; lapa[t] = 0.f; }
    float den = 0.f;

    for (int kb = 0; kb < c; kb += 4) {
        int jr4[4]; float lv4[4], in4[4], hd4[4][9];
        #pragma unroll
        for (int q = 0; q < 4; ++q) {            // k <= 63 always (pads=self)
            const int k = kb + q;
            jr4[q] = brow | __shfl(j_lane, k);   // uniform k -> readlane
            lv4[q] = __shfl(lv_lane, k);
            in4[q] = inp[jr4[q]];
        }
        #pragma unroll
        for (int q = 0; q < 4; ++q) {            // 9 independent loads/edge
            #pragma unroll
            for (int t = 0; t < 9; ++t) {
                const int d = dg + 8 * t;
                float v = 0.f;
                if (d == 0)       v = in4[q];
                else if (d <= 64) v = hid[jr4[q] * 64 + d - 1];
                hd4[q][t] = v;
            }
        }
        #pragma unroll
        for (int q = 0; q < 4; ++q) {
            float ed = 0.f;
            #pragma unroll
            for (int t = 0; t < 9; ++t) ed = fmaf(hd4[q][t], wdr[t], ed);
            ed += __shfl_xor(ed, 1); ed += __shfl_xor(ed, 2); ed += __shfl_xor(ed, 4);
            float s = es_h + ed;
            s = (s > 0.f) ? s : 0.2f * s;        // leaky_relu(0.2)
            const float p = (kb + q < c) ? __expf(s) : 0.f;
            den += p;                            // uniform within 8-lane group
            #pragma unroll
            for (int t = 0; t < 9; ++t) {
                agg[t]  = fmaf(p,      hd4[q][t], agg[t]);
                lapa[t] = fmaf(lv4[q], hd4[q][t], lapa[t]);
            }
        }
    }

    // ---- publish aggregates to wave-local LDS, project through W/W2 ----
    #pragma unroll
    for (int t = 0; t < 9; ++t) {
        const int d = dg + 8 * t;
        if (d <= 64) {
            agg_s[wid][h][d] = agg[t];
            if (h == 0) lapa_s[wid][d] = lapa[t];
        }
    }
    __syncthreads();                             // cheap; guarantees LDS RAW

    float accg = 0.f, accl = 0.f;
    for (int d = 0; d <= 64; ++d) {              // lane = output column
        accg = fmaf(agg_s[wid][lane >> 3][d], W [d * 64 + lane], accg);
        accl = fmaf(lapa_s[wid][d],           W2[d * 64 + lane], accl);
    }

    out[row * 128 + lane]      = accg / den;
    out[row * 128 + 64 + lane] = accl + biases[lane];
}

// ---------------------------------------------------------------------------
extern "C" void kernel_launch(void* const* d_in, const int* in_sizes, int n_in,
                              void* d_out, int out_size, void* d_ws, size_t ws_size,
                              hipStream_t stream) {
    const float* inp    = (const float*)d_in[0];  // (4,1024,1)
    const float* hid    = (const float*)d_in[1];  // (4,1024,64)
    const float* W      = (const float*)d_in[2];  // (65,64)
    const float* attnv  = (const float*)d_in[3];  // (16,1)
    const float* W2     = (const float*)d_in[4];  // (65,64) "weights"
    const float* biases = (const float*)d_in[5];  // (64,)
    const float* adj    = (const float*)d_in[6];  // (1024,1024)
    const float* lap    = (const float*)d_in[7];  // (1024,1024)
    float* out = (float*)d_out;
    // d_ws: UNUSED — no workspace, no memset node, no cross-block state.

    fused_one<<<NN, 256, 0, stream>>>(
        adj, lap, inp, hid, W, W2, attnv, biases, out);
}